// Round 9
// baseline (332.400 us; speedup 1.0000x reference)
//
#include <hip/hip_runtime.h>
#include <math.h>

#define B_    256
#define S_    128
#define ENCD  1024
#define DECU  512
#define UNITS 1024
#define VOCAB 32000
#define EMB_  300
#define INDIM 1324   // ENCD + EMB
#define KPADX 1344   // INDIM padded to 64
#define G3    3072   // 3*UNITS

typedef __bf16 bf16x8 __attribute__((ext_vector_type(8)));
typedef __bf16 bf16x4 __attribute__((ext_vector_type(4)));
typedef __bf16 bf16x2 __attribute__((ext_vector_type(2)));
typedef float  f32x4  __attribute__((ext_vector_type(4)));

#define MFMA16(a, b, c) __builtin_amdgcn_mfma_f32_16x16x32_bf16((a), (b), (c), 0, 0, 0)

// LDS tile: row stride 64 bf16 (128 B), XOR-swizzled 16B slots: bank-conflict-free b128
// (measured: SQ_LDS_BANK_CONFLICT == 0 since R5).
__device__ __forceinline__ int swz(int row, int e) { return row * 64 + (e ^ ((row & 7) << 3)); }

__device__ __forceinline__ float fast_tanh(float x) {
  x = fminf(fmaxf(x, -15.f), 15.f);
  float e = __expf(2.f * x);
  return (e - 1.f) / (e + 1.f);
}

// ---------------- convert state f32 -> bf16 ----------------
__global__ __launch_bounds__(256) void k_cvt_state(const float* __restrict__ in,
                                                   __bf16* __restrict__ out) {
  int i4 = blockIdx.x * 256 + threadIdx.x;   // 65536 float4s
  float4 f = *(const float4*)(in + (size_t)i4 * 4);
  bf16x4 o = {(__bf16)f.x, (__bf16)f.y, (__bf16)f.z, (__bf16)f.w};
  *(bf16x4*)(out + (size_t)i4 * 4) = o;
}

// ---------------- transpose+convert W1 [1024][512] f32 -> W1t [512][1024] bf16 ----------------
__global__ __launch_bounds__(1024) void k_w1t(const float* __restrict__ W1,
                                              __bf16* __restrict__ W1t) {
  int n = blockIdx.x;      // 512
  int k = threadIdx.x;     // 1024
  W1t[(size_t)n * 1024 + k] = (__bf16)W1[(size_t)k * 512 + n];
}

// ============ generic MFMA GEMM: C[M][N] = A_bf[M][ldaK] @ B_f32[K][N] + bias ============
// BN=64, BK=64, 512 threads (8 waves), swizzled LDS, reg-prefetch pipeline.
template <int BM>
__global__ __launch_bounds__(512) void k_gemm(const __bf16* __restrict__ A, int ldaK,
                                              const float* __restrict__ B,
                                              const float* __restrict__ bias,
                                              float* __restrict__ C, int K, int N) {
  constexpr int WR = (BM == 64) ? 2 : 4;
  constexpr int WN = 8 / WR;
  constexpr int MI = BM / (WR * 16);
  constexpr int NI = 64 / (WN * 16);
  __shared__ __align__(16) __bf16 As[BM * 64];
  __shared__ __align__(16) __bf16 Bs[64 * 64];
  int tid = threadIdx.x, lane = tid & 63, w = tid >> 6;
  int wr = w / WN, wn = w % WN;
  int m0 = blockIdx.x * BM, n0 = blockIdx.y * 64;
  int lrow = lane & 15, lk = (lane >> 4) * 8;
  int r0 = wr * MI * 16, c0 = wn * NI * 16;
  f32x4 acc[MI][NI] = {};

  constexpr int ACH = BM / 64;        // bf16x8 chunks per thread (A)
  constexpr int TPR = 8 / ACH;        // threads per A row
  bf16x8 pfa[ACH];
  float pfb[8];
  int am = tid / TPR, aks = (tid % TPR) * (ACH * 8);
  const __bf16* arow = A + (size_t)(m0 + am) * ldaK + aks;
  int bn = tid & 63, bks = (tid >> 6) * 8;

  int nk = (K + 63) >> 6;
#pragma unroll
  for (int c = 0; c < ACH; ++c) pfa[c] = *(const bf16x8*)(arow + c * 8);
#pragma unroll
  for (int i = 0; i < 8; ++i) { int k = bks + i; pfb[i] = (k < K) ? B[(size_t)k * N + n0 + bn] : 0.f; }

  for (int it = 0; it < nk; ++it) {
#pragma unroll
    for (int c = 0; c < ACH; ++c) *(bf16x8*)&As[swz(am, aks + c * 8)] = pfa[c];
    {
      __bf16 tb[8];
#pragma unroll
      for (int i = 0; i < 8; ++i) tb[i] = (__bf16)pfb[i];
      *(bf16x8*)&Bs[swz(bn, bks)] = *(bf16x8*)&tb[0];
    }
    __syncthreads();
    if (it + 1 < nk) {
      int k0 = (it + 1) * 64;
#pragma unroll
      for (int c = 0; c < ACH; ++c) pfa[c] = *(const bf16x8*)(arow + k0 + c * 8);
#pragma unroll
      for (int i = 0; i < 8; ++i) { int k = k0 + bks + i; pfb[i] = (k < K) ? B[(size_t)k * N + n0 + bn] : 0.f; }
    }
#pragma unroll
    for (int kk = 0; kk < 64; kk += 32) {
      bf16x8 av[MI], bv[NI];
#pragma unroll
      for (int mi = 0; mi < MI; ++mi) { int r = r0 + mi * 16 + lrow; av[mi] = *(bf16x8*)&As[swz(r, kk + lk)]; }
#pragma unroll
      for (int ni = 0; ni < NI; ++ni) { int r = c0 + ni * 16 + lrow; bv[ni] = *(bf16x8*)&Bs[swz(r, kk + lk)]; }
#pragma unroll
      for (int mi = 0; mi < MI; ++mi)
#pragma unroll
        for (int ni = 0; ni < NI; ++ni) acc[mi][ni] = MFMA16(av[mi], bv[ni], acc[mi][ni]);
    }
    __syncthreads();
  }
#pragma unroll
  for (int mi = 0; mi < MI; ++mi)
#pragma unroll
    for (int ni = 0; ni < NI; ++ni) {
      int colg = n0 + c0 + ni * 16 + lrow;
      float bvv = bias[colg];
#pragma unroll
      for (int reg = 0; reg < 4; ++reg) {
        int rowg = m0 + r0 + mi * 16 + (lane >> 4) * 4 + reg;
        C[(size_t)rowg * N + colg] = acc[mi][ni][reg] + bvv;
      }
    }
}

// ============ score v5: barrier-free direct-fragment GEMM ============
// No LDS, no __syncthreads in the K-loop. Each wave owns 32 rows x 128 j.
// A (enc f32) and B (W1t bf16, L2-hot) fragments loaded straight from global
// in MFMA lane layout: lane l -> row base+(l&15), k slice k0+(l>>4)*8.
// 1-D grid of 1024; XCD-aware mapping keeps the 4 j-tiles of one b on one XCD.
__global__ __launch_bounds__(256, 4) void k_score5(const float* __restrict__ enc,
                                                   const __bf16* __restrict__ W1t,
                                                   const float* __restrict__ b1,
                                                   const float* __restrict__ q,
                                                   const float* __restrict__ V,
                                                   float* __restrict__ sc_part) {
  int wg = blockIdx.x;                  // 0..1023
  int xcd = wg & 7, grp = wg >> 3;      // dispatch round-robins wg over 8 XCDs
  int by = grp & 3;
  int b = xcd * 32 + (grp >> 2);        // 4 by-blocks of b share an XCD's L2
  int n0 = by * 128;
  int tid = threadIdx.x, lane = tid & 63, w = tid >> 6;
  int lrow = lane & 15, lk = (lane >> 4) * 8;
  f32x4 acc[2][8] = {};

  const float*  ar0 = enc + (size_t)(b * 128 + w * 32 + lrow) * ENCD + lk;   // mi=0 rows
  const float*  ar1 = ar0 + 16 * ENCD;                                       // mi=1 rows
  const __bf16* br  = W1t + (size_t)(n0 + lrow) * 1024 + lk;                 // + ni*16*1024

  for (int k0 = 0; k0 < ENCD; k0 += 32) {
    // A fragments: f32 -> bf16 in-register
    float4 f0 = *(const float4*)(ar0 + k0);
    float4 f1 = *(const float4*)(ar0 + k0 + 4);
    float4 g0 = *(const float4*)(ar1 + k0);
    float4 g1 = *(const float4*)(ar1 + k0 + 4);
    bf16x8 a0 = {(__bf16)f0.x, (__bf16)f0.y, (__bf16)f0.z, (__bf16)f0.w,
                 (__bf16)f1.x, (__bf16)f1.y, (__bf16)f1.z, (__bf16)f1.w};
    bf16x8 a1 = {(__bf16)g0.x, (__bf16)g0.y, (__bf16)g0.z, (__bf16)g0.w,
                 (__bf16)g1.x, (__bf16)g1.y, (__bf16)g1.z, (__bf16)g1.w};
#pragma unroll
    for (int ni = 0; ni < 8; ++ni) {
      bf16x8 bv = *(const bf16x8*)(br + (size_t)ni * 16 * 1024 + k0);
      acc[0][ni] = MFMA16(a0, bv, acc[0][ni]);
      acc[1][ni] = MFMA16(a1, bv, acc[1][ni]);
    }
  }
  // epilogue: tanh + dot V over this block's 128 j (all in-register per wave)
  float psum[2][4] = {};
#pragma unroll
  for (int mi = 0; mi < 2; ++mi)
#pragma unroll
    for (int ni = 0; ni < 8; ++ni) {
      int j = n0 + ni * 16 + lrow;
      float vj = V[j], b1j = b1[j], qv = q[(size_t)b * DECU + j];
#pragma unroll
      for (int reg = 0; reg < 4; ++reg)
        psum[mi][reg] += vj * fast_tanh(acc[mi][ni][reg] + b1j + qv);
    }
#pragma unroll
  for (int off = 1; off < 16; off <<= 1)
#pragma unroll
    for (int mi = 0; mi < 2; ++mi)
#pragma unroll
      for (int reg = 0; reg < 4; ++reg)
        psum[mi][reg] += __shfl_xor(psum[mi][reg], off);
  if (lrow == 0) {
#pragma unroll
    for (int mi = 0; mi < 2; ++mi)
#pragma unroll
      for (int reg = 0; reg < 4; ++reg) {
        int m = w * 32 + mi * 16 + (lane >> 4) * 4 + reg;
        sc_part[((size_t)b * 128 + m) * 4 + by] = psum[mi][reg];
      }
  }
}

// ---------------- softmax over S + context + xi assembly; grid (256 b, 4 col-chunks) ----------------
__global__ __launch_bounds__(256) void k_ctx3(const float* __restrict__ sc_part,
                                              const float* __restrict__ bV,
                                              const float* __restrict__ enc,
                                              const int* __restrict__ x,
                                              const float* __restrict__ emb,
                                              float* __restrict__ attn_out,
                                              __bf16* __restrict__ xi_bf) {
  int b = blockIdx.x, chunk = blockIdx.y, t = threadIdx.x;
  int lane = t & 63, w = t >> 6;
  __shared__ float a_s[S_];
  __shared__ float part[4][256];
  if (t < S_) {
    float4 p = *(const float4*)&sc_part[((size_t)b * 128 + t) * 4];
    a_s[t] = bV[0] + p.x + p.y + p.z + p.w;
  }
  __syncthreads();
  float mx = -INFINITY;
  for (int s = 0; s < S_; ++s) mx = fmaxf(mx, a_s[s]);
  float sum = 0.f;
  for (int s = 0; s < S_; ++s) sum += __expf(a_s[s] - mx);
  float inv = 1.f / sum;
  __syncthreads();
  if (t < S_) {
    float av = __expf(a_s[t] - mx) * inv;
    a_s[t] = av;
    if (chunk == 0) attn_out[(size_t)b * S_ + t] = av;
  }
  __syncthreads();
  // context cols [chunk*256, chunk*256+256): wave w covers s in [w*32, w*32+32), 4 cols/lane
  int c0 = chunk * 256;
  float a0 = 0.f, a1 = 0.f, a2 = 0.f, a3 = 0.f;
  const float* eb = enc + ((size_t)b * S_ + w * 32) * ENCD + c0 + lane * 4;
#pragma unroll 8
  for (int s = 0; s < 32; ++s) {
    float av = a_s[w * 32 + s];
    float4 e = *(const float4*)(eb + (size_t)s * ENCD);
    a0 = fmaf(av, e.x, a0); a1 = fmaf(av, e.y, a1);
    a2 = fmaf(av, e.z, a2); a3 = fmaf(av, e.w, a3);
  }
  part[w][lane * 4 + 0] = a0; part[w][lane * 4 + 1] = a1;
  part[w][lane * 4 + 2] = a2; part[w][lane * 4 + 3] = a3;
  __syncthreads();
  float v = part[0][t] + part[1][t] + part[2][t] + part[3][t];
  xi_bf[(size_t)b * KPADX + c0 + t] = (__bf16)v;
  // embedding + pad -> xi_bf[1024:1344] (chunk 0 only)
  if (chunk == 0) {
    int xb = x[b];
    if (t < 75) {
      float4 f = *(const float4*)&emb[(size_t)xb * EMB_ + t * 4];
      bf16x4 o4 = {(__bf16)f.x, (__bf16)f.y, (__bf16)f.z, (__bf16)f.w};
      *(bf16x4*)&xi_bf[(size_t)b * KPADX + ENCD + t * 4] = o4;
    } else if (t < 80) {
      bf16x4 z = {(__bf16)0.f, (__bf16)0.f, (__bf16)0.f, (__bf16)0.f};
      *(bf16x4*)&xi_bf[(size_t)b * KPADX + INDIM + (t - 75) * 4] = z;
    }
  }
}

// ---------------- GRU gates (+ h in bf16) ----------------
__global__ __launch_bounds__(256) void k_gates(const float* __restrict__ mx,
                                               const float* __restrict__ mh,
                                               const float* __restrict__ state,
                                               float* __restrict__ h_out,
                                               __bf16* __restrict__ h_bf) {
  int idx = blockIdx.x * 256 + threadIdx.x;
  int b = idx >> 10, j = idx & 1023;
  const float* mxr = mx + (size_t)b * G3;
  const float* mhr = mh + (size_t)b * G3;
  float z = 1.f / (1.f + __expf(-(mxr[j] + mhr[j])));
  float r = 1.f / (1.f + __expf(-(mxr[UNITS + j] + mhr[UNITS + j])));
  float hh = tanhf(mxr[2 * UNITS + j] + r * mhr[2 * UNITS + j]);
  float st = state[idx];
  float h = z * st + (1.f - z) * hh;
  h_out[idx] = h;
  h_bf[idx] = (__bf16)h;
}

// ---------------- register-resident vocab softmax ----------------
__global__ __launch_bounds__(1024) void k_softmax(float* __restrict__ logits) {
  int b = blockIdx.x, t = threadIdx.x;
  int lane = t & 63, w = t >> 6;
  float4* row4 = (float4*)(logits + (size_t)b * VOCAB);  // 8000 float4
  __shared__ float redm[16];
  __shared__ float reds[16];
  float4 v[8];
  float m = -INFINITY;
#pragma unroll
  for (int i = 0; i < 8; ++i) {
    int i4 = i * 1024 + t;
    if (i4 < 8000) {
      v[i] = row4[i4];
      m = fmaxf(m, fmaxf(fmaxf(v[i].x, v[i].y), fmaxf(v[i].z, v[i].w)));
    } else {
      v[i] = make_float4(-INFINITY, -INFINITY, -INFINITY, -INFINITY);
    }
  }
#pragma unroll
  for (int o = 32; o >= 1; o >>= 1) m = fmaxf(m, __shfl_xor(m, o));
  if (lane == 0) redm[w] = m;
  __syncthreads();
  float m2 = -INFINITY;
#pragma unroll
  for (int i = 0; i < 16; ++i) m2 = fmaxf(m2, redm[i]);
  float s = 0.f;
#pragma unroll
  for (int i = 0; i < 8; ++i) {
    v[i].x = __expf(v[i].x - m2);
    v[i].y = __expf(v[i].y - m2);
    v[i].z = __expf(v[i].z - m2);
    v[i].w = __expf(v[i].w - m2);
    s += v[i].x + v[i].y + v[i].z + v[i].w;
  }
#pragma unroll
  for (int o = 32; o >= 1; o >>= 1) s += __shfl_xor(s, o);
  if (lane == 0) reds[w] = s;
  __syncthreads();
  float s2 = 0.f;
#pragma unroll
  for (int i = 0; i < 16; ++i) s2 += reds[i];
  float inv = 1.f / s2;
#pragma unroll
  for (int i = 0; i < 8; ++i) {
    int i4 = i * 1024 + t;
    if (i4 < 8000)
      row4[i4] = make_float4(v[i].x * inv, v[i].y * inv, v[i].z * inv, v[i].w * inv);
  }
}

extern "C" void kernel_launch(void* const* d_in, const int* in_sizes, int n_in,
                              void* d_out, int out_size, void* d_ws, size_t ws_size,
                              hipStream_t stream) {
  const int*   x     = (const int*)d_in[0];
  const float* state = (const float*)d_in[1];
  const float* enc   = (const float*)d_in[2];
  const float* emb   = (const float*)d_in[3];
  const float* W1    = (const float*)d_in[4];
  const float* b1    = (const float*)d_in[5];
  const float* W2    = (const float*)d_in[6];
  const float* b2    = (const float*)d_in[7];
  const float* V     = (const float*)d_in[8];
  const float* bV    = (const float*)d_in[9];
  const float* gru_k = (const float*)d_in[10];
  const float* gru_rk= (const float*)d_in[11];
  const float* gru_b = (const float*)d_in[12];
  const float* fc_W  = (const float*)d_in[13];
  const float* fc_b  = (const float*)d_in[14];

  float* out   = (float*)d_out;
  float* probs = out;                               // 256*32000
  float* h_out = out + (size_t)B_ * VOCAB;          // 256*1024
  float* attn  = h_out + (size_t)B_ * UNITS;        // 256*128

  float* ws = (float*)d_ws;
  float* q       = ws;                              // 131072 f32
  float* sc_part = q + (size_t)B_ * DECU;           // 131072 f32 (32768 x 4)
  float* mx      = sc_part + (size_t)B_ * S_ * 4;   // 786432 f32
  float* mh      = mx + (size_t)B_ * G3;            // 786432 f32
  __bf16* state_bf = (__bf16*)(mh + (size_t)B_ * G3);   // 262144 bf16
  __bf16* xi_bf    = state_bf + (size_t)B_ * UNITS;     // 256*1344 bf16
  __bf16* h_bf     = xi_bf + (size_t)B_ * KPADX;        // 262144 bf16
  __bf16* W1t      = h_bf + (size_t)B_ * UNITS;         // 512*1024 bf16

  k_cvt_state<<<256, 256, 0, stream>>>(state, state_bf);
  k_w1t<<<512, 1024, 0, stream>>>(W1, W1t);
  // q = state @ W2 + b2
  k_gemm<64><<<dim3(4, 8), 512, 0, stream>>>(state_bf, UNITS, W2, b2, q, UNITS, DECU);
  // score partials: barrier-free direct-fragment GEMM (1024 blocks, XCD-mapped)
  k_score5<<<1024, 256, 0, stream>>>(enc, W1t, b1, q, V, sc_part);
  // softmax + context + xi (4 col-chunks per b)
  k_ctx3<<<dim3(B_, 4), 256, 0, stream>>>(sc_part, bV, enc, x, emb, attn, xi_bf);
  // GRU GEMMs
  k_gemm<64><<<dim3(4, 48), 512, 0, stream>>>(xi_bf, KPADX, gru_k, gru_b, mx, INDIM, G3);
  k_gemm<64><<<dim3(4, 48), 512, 0, stream>>>(state_bf, UNITS, gru_rk, gru_b + G3, mh, UNITS, G3);
  // gates -> h
  k_gates<<<(B_ * UNITS) / 256, 256, 0, stream>>>(mx, mh, state, h_out, h_bf);
  // FC logits (BM=256, BN=64: 500 blocks)
  k_gemm<256><<<dim3(1, VOCAB / 64), 512, 0, stream>>>(h_bf, UNITS, fc_W, fc_b, probs, UNITS, VOCAB);
  // vocab softmax
  k_softmax<<<B_, 1024, 0, stream>>>(probs);
}

// Round 10
// 234.650 us; speedup vs baseline: 1.4166x; 1.4166x over previous
//
#include <hip/hip_runtime.h>
#include <math.h>

#define B_    256
#define S_    128
#define ENCD  1024
#define DECU  512
#define UNITS 1024
#define VOCAB 32000
#define EMB_  300
#define INDIM 1324   // ENCD + EMB
#define KPADX 1344   // INDIM padded to 64
#define G3    3072   // 3*UNITS

typedef __bf16 bf16x8 __attribute__((ext_vector_type(8)));
typedef __bf16 bf16x4 __attribute__((ext_vector_type(4)));
typedef __bf16 bf16x2 __attribute__((ext_vector_type(2)));
typedef float  f32x4  __attribute__((ext_vector_type(4)));

#define MFMA16(a, b, c) __builtin_amdgcn_mfma_f32_16x16x32_bf16((a), (b), (c), 0, 0, 0)

// LDS tile: row stride 64 bf16 (128 B), XOR-swizzled 16B slots: bank-conflict-free b128
// (measured: SQ_LDS_BANK_CONFLICT == 0 since R5).
__device__ __forceinline__ int swz(int row, int e) { return row * 64 + (e ^ ((row & 7) << 3)); }

// async global->LDS, 16B/lane; LDS dest is wave-uniform base + lane*16 (linear).
__device__ __forceinline__ void gl_lds16(const void* g, void* l) {
  __builtin_amdgcn_global_load_lds((const __attribute__((address_space(1))) void*)g,
                                   (__attribute__((address_space(3))) void*)l, 16, 0, 0);
}

__device__ __forceinline__ float fast_tanh(float x) {
  x = fminf(fmaxf(x, -15.f), 15.f);
  float e = __expf(2.f * x);
  return (e - 1.f) / (e + 1.f);
}

// ---------------- convert enc f32 -> bf16 (grid-stride over bf16x8 groups) ----------------
__global__ __launch_bounds__(256) void k_cvt_enc(const float* __restrict__ in,
                                                 __bf16* __restrict__ out) {
  for (int g = blockIdx.x * 256 + threadIdx.x; g < (B_ * S_ * ENCD) / 8; g += 4096 * 256) {
    const float* p = in + (size_t)g * 8;
    float4 f0 = *(const float4*)p;
    float4 f1 = *(const float4*)(p + 4);
    bf16x8 o = {(__bf16)f0.x, (__bf16)f0.y, (__bf16)f0.z, (__bf16)f0.w,
                (__bf16)f1.x, (__bf16)f1.y, (__bf16)f1.z, (__bf16)f1.w};
    *(bf16x8*)(out + (size_t)g * 8) = o;
  }
}

// ---------------- convert state f32 -> bf16 ----------------
__global__ __launch_bounds__(256) void k_cvt_state(const float* __restrict__ in,
                                                   __bf16* __restrict__ out) {
  int i4 = blockIdx.x * 256 + threadIdx.x;   // 65536 float4s
  float4 f = *(const float4*)(in + (size_t)i4 * 4);
  bf16x4 o = {(__bf16)f.x, (__bf16)f.y, (__bf16)f.z, (__bf16)f.w};
  *(bf16x4*)(out + (size_t)i4 * 4) = o;
}

// ---------------- transpose+convert W1 [1024][512] f32 -> W1t [512][1024] bf16 ----------------
__global__ __launch_bounds__(1024) void k_w1t(const float* __restrict__ W1,
                                              __bf16* __restrict__ W1t) {
  int n = blockIdx.x;      // 512
  int k = threadIdx.x;     // 1024
  W1t[(size_t)n * 1024 + k] = (__bf16)W1[(size_t)k * 512 + n];
}

// ============ generic MFMA GEMM: C[M][N] = A_bf[M][ldaK] @ B_f32[K][N] + bias ============
// BN=64, BK=64, 512 threads (8 waves), swizzled LDS, reg-prefetch pipeline.
template <int BM>
__global__ __launch_bounds__(512) void k_gemm(const __bf16* __restrict__ A, int ldaK,
                                              const float* __restrict__ B,
                                              const float* __restrict__ bias,
                                              float* __restrict__ C, int K, int N) {
  constexpr int WR = (BM == 64) ? 2 : 4;
  constexpr int WN = 8 / WR;
  constexpr int MI = BM / (WR * 16);
  constexpr int NI = 64 / (WN * 16);
  __shared__ __align__(16) __bf16 As[BM * 64];
  __shared__ __align__(16) __bf16 Bs[64 * 64];
  int tid = threadIdx.x, lane = tid & 63, w = tid >> 6;
  int wr = w / WN, wn = w % WN;
  int m0 = blockIdx.x * BM, n0 = blockIdx.y * 64;
  int lrow = lane & 15, lk = (lane >> 4) * 8;
  int r0 = wr * MI * 16, c0 = wn * NI * 16;
  f32x4 acc[MI][NI] = {};

  constexpr int ACH = BM / 64;        // bf16x8 chunks per thread (A)
  constexpr int TPR = 8 / ACH;        // threads per A row
  bf16x8 pfa[ACH];
  float pfb[8];
  int am = tid / TPR, aks = (tid % TPR) * (ACH * 8);
  const __bf16* arow = A + (size_t)(m0 + am) * ldaK + aks;
  int bn = tid & 63, bks = (tid >> 6) * 8;

  int nk = (K + 63) >> 6;
#pragma unroll
  for (int c = 0; c < ACH; ++c) pfa[c] = *(const bf16x8*)(arow + c * 8);
#pragma unroll
  for (int i = 0; i < 8; ++i) { int k = bks + i; pfb[i] = (k < K) ? B[(size_t)k * N + n0 + bn] : 0.f; }

  for (int it = 0; it < nk; ++it) {
#pragma unroll
    for (int c = 0; c < ACH; ++c) *(bf16x8*)&As[swz(am, aks + c * 8)] = pfa[c];
    {
      __bf16 tb[8];
#pragma unroll
      for (int i = 0; i < 8; ++i) tb[i] = (__bf16)pfb[i];
      *(bf16x8*)&Bs[swz(bn, bks)] = *(bf16x8*)&tb[0];
    }
    __syncthreads();
    if (it + 1 < nk) {
      int k0 = (it + 1) * 64;
#pragma unroll
      for (int c = 0; c < ACH; ++c) pfa[c] = *(const bf16x8*)(arow + k0 + c * 8);
#pragma unroll
      for (int i = 0; i < 8; ++i) { int k = k0 + bks + i; pfb[i] = (k < K) ? B[(size_t)k * N + n0 + bn] : 0.f; }
    }
#pragma unroll
    for (int kk = 0; kk < 64; kk += 32) {
      bf16x8 av[MI], bv[NI];
#pragma unroll
      for (int mi = 0; mi < MI; ++mi) { int r = r0 + mi * 16 + lrow; av[mi] = *(bf16x8*)&As[swz(r, kk + lk)]; }
#pragma unroll
      for (int ni = 0; ni < NI; ++ni) { int r = c0 + ni * 16 + lrow; bv[ni] = *(bf16x8*)&Bs[swz(r, kk + lk)]; }
#pragma unroll
      for (int mi = 0; mi < MI; ++mi)
#pragma unroll
        for (int ni = 0; ni < NI; ++ni) acc[mi][ni] = MFMA16(av[mi], bv[ni], acc[mi][ni]);
    }
    __syncthreads();
  }
#pragma unroll
  for (int mi = 0; mi < MI; ++mi)
#pragma unroll
    for (int ni = 0; ni < NI; ++ni) {
      int colg = n0 + c0 + ni * 16 + lrow;
      float bvv = bias[colg];
#pragma unroll
      for (int reg = 0; reg < 4; ++reg) {
        int rowg = m0 + r0 + mi * 16 + (lane >> 4) * 4 + reg;
        C[(size_t)rowg * N + colg] = acc[mi][ni][reg] + bvv;
      }
    }
}

// ============ score v6: m97-clone — both tiles via global_load_lds(16), zero VALU staging ====
// A = enc_bf [32768][1024], B = W1t [512][1024]. 128x128 tile, BK=64, 4 waves, 32KB LDS,
// single buffer, 2 barriers/iter. LDS dest linear, source pre-swizzled (validated in R8).
// grid (256 b, 4 j-tiles). Output: sc_part[row][4] (pre-softmax, V-contracted).
__global__ __launch_bounds__(256) void k_score6(const __bf16* __restrict__ enc_bf,
                                                const __bf16* __restrict__ W1t,
                                                const float* __restrict__ b1,
                                                const float* __restrict__ q,
                                                const float* __restrict__ V,
                                                float* __restrict__ sc_part) {
  __shared__ __align__(16) __bf16 As[128 * 64];
  __shared__ __align__(16) __bf16 Bs[128 * 64];
  __shared__ float red[2][128];
  int b = blockIdx.x, by = blockIdx.y;
  int m0 = b * 128, n0 = by * 128;
  int tid = threadIdx.x, lane = tid & 63, w = tid >> 6;
  int wr = w >> 1, wn = w & 1;
  int lrow = lane & 15, lk = (lane >> 4) * 8;
  int r0 = wr * 64, c0 = wn * 64;
  f32x4 acc[4][4] = {};

  // gl_lds geometry: wave w stages 16B-chunks [w*4, w*4+4) of each 8KB tile.
  // chunk ch, lane l -> LDS row ch*8 + (l>>3), physical slot l&7.
  // Swizzled content: physical slot p of row r holds logical slot p ^ (r&7).
  int srow = lane >> 3;
  int sslot = (lane & 7) ^ (srow & 7);
  const __bf16* asrc[4];
  const __bf16* bsrc[4];
#pragma unroll
  for (int c = 0; c < 4; ++c) {
    int row = (w * 4 + c) * 8 + srow;
    asrc[c] = enc_bf + (size_t)(m0 + row) * 1024 + sslot * 8;
    bsrc[c] = W1t + (size_t)(n0 + row) * 1024 + sslot * 8;
  }

  for (int it = 0; it < 16; ++it) {
    int k0 = it * 64;
#pragma unroll
    for (int c = 0; c < 4; ++c) gl_lds16(asrc[c] + k0, &As[(w * 4 + c) * 512]);
#pragma unroll
    for (int c = 0; c < 4; ++c) gl_lds16(bsrc[c] + k0, &Bs[(w * 4 + c) * 512]);
    __syncthreads();   // drains vmcnt -> staged data visible
#pragma unroll
    for (int kk = 0; kk < 64; kk += 32) {
      bf16x8 av[4], bv[4];
#pragma unroll
      for (int mi = 0; mi < 4; ++mi) { int r = r0 + mi * 16 + lrow; av[mi] = *(bf16x8*)&As[swz(r, kk + lk)]; }
#pragma unroll
      for (int ni = 0; ni < 4; ++ni) { int r = c0 + ni * 16 + lrow; bv[ni] = *(bf16x8*)&Bs[swz(r, kk + lk)]; }
#pragma unroll
      for (int mi = 0; mi < 4; ++mi)
#pragma unroll
        for (int ni = 0; ni < 4; ++ni) acc[mi][ni] = MFMA16(av[mi], bv[ni], acc[mi][ni]);
    }
    __syncthreads();   // all waves done reading before next overwrite
  }
  // ---- epilogue: tanh + dot V over this block's 128 j
  float psum[4][4] = {};
#pragma unroll
  for (int mi = 0; mi < 4; ++mi)
#pragma unroll
    for (int ni = 0; ni < 4; ++ni) {
      int j = n0 + c0 + ni * 16 + lrow;
      float vj = V[j], b1j = b1[j], qv = q[(size_t)b * DECU + j];
#pragma unroll
      for (int reg = 0; reg < 4; ++reg)
        psum[mi][reg] += vj * fast_tanh(acc[mi][ni][reg] + b1j + qv);
    }
#pragma unroll
  for (int off = 1; off < 16; off <<= 1)
#pragma unroll
    for (int mi = 0; mi < 4; ++mi)
#pragma unroll
      for (int reg = 0; reg < 4; ++reg)
        psum[mi][reg] += __shfl_xor(psum[mi][reg], off);
  if (lrow == 0) {
#pragma unroll
    for (int mi = 0; mi < 4; ++mi)
#pragma unroll
      for (int reg = 0; reg < 4; ++reg)
        red[wn][r0 + mi * 16 + (lane >> 4) * 4 + reg] = psum[mi][reg];
  }
  __syncthreads();
  if (tid < 128)
    sc_part[((size_t)b * 128 + tid) * 4 + by] = red[0][tid] + red[1][tid];
}

// ============ score v2 (fallback when ws too small): reg-staged 2-phase ============
__global__ __launch_bounds__(256) void k_score2(const float* __restrict__ enc,
                                                const __bf16* __restrict__ W1t,
                                                const float* __restrict__ b1,
                                                const float* __restrict__ q,
                                                const float* __restrict__ V,
                                                float* __restrict__ sc_part) {
  __shared__ __align__(16) __bf16 As[128 * 64];
  __shared__ __align__(16) __bf16 Bs[128 * 64];
  __shared__ float red[2][128];
  int b = blockIdx.x, by = blockIdx.y;
  int n0 = by * 128;
  int tid = threadIdx.x, lane = tid & 63, w = tid >> 6;
  int wr = w >> 1, wn = w & 1;
  int lrow = lane & 15, lk = (lane >> 4) * 8;
  int r0 = wr * 64, c0 = wn * 64;
  f32x4 acc[4][4] = {};
  int am = tid >> 1, aks = (tid & 1) * 32;
  const float* ap0 = enc + ((size_t)b * 128 + am) * ENCD + aks;
  int bn = tid >> 1, bks = (tid & 1) * 32;
  const __bf16* bp0 = W1t + (size_t)(n0 + bn) * 1024 + bks;
  for (int it = 0; it < 16; ++it) {
    int k0 = it * 64;
    {
      const float* ap = ap0 + k0;
      float4 f[8];
#pragma unroll
      for (int c = 0; c < 8; ++c) f[c] = *(const float4*)(ap + c * 4);
      __bf16 t[32];
#pragma unroll
      for (int c = 0; c < 8; ++c) {
        t[c * 4 + 0] = (__bf16)f[c].x; t[c * 4 + 1] = (__bf16)f[c].y;
        t[c * 4 + 2] = (__bf16)f[c].z; t[c * 4 + 3] = (__bf16)f[c].w;
      }
#pragma unroll
      for (int c = 0; c < 4; ++c) *(bf16x8*)&As[swz(am, aks + c * 8)] = *(bf16x8*)&t[c * 8];
    }
    {
      const __bf16* bp = bp0 + k0;
#pragma unroll
      for (int c = 0; c < 4; ++c)
        *(bf16x8*)&Bs[swz(bn, bks + c * 8)] = *(const bf16x8*)(bp + c * 8);
    }
    __syncthreads();
#pragma unroll
    for (int kk = 0; kk < 64; kk += 32) {
      bf16x8 av[4], bv[4];
#pragma unroll
      for (int mi = 0; mi < 4; ++mi) { int r = r0 + mi * 16 + lrow; av[mi] = *(bf16x8*)&As[swz(r, kk + lk)]; }
#pragma unroll
      for (int ni = 0; ni < 4; ++ni) { int r = c0 + ni * 16 + lrow; bv[ni] = *(bf16x8*)&Bs[swz(r, kk + lk)]; }
#pragma unroll
      for (int mi = 0; mi < 4; ++mi)
#pragma unroll
        for (int ni = 0; ni < 4; ++ni) acc[mi][ni] = MFMA16(av[mi], bv[ni], acc[mi][ni]);
    }
    __syncthreads();
  }
  float psum[4][4] = {};
#pragma unroll
  for (int mi = 0; mi < 4; ++mi)
#pragma unroll
    for (int ni = 0; ni < 4; ++ni) {
      int j = n0 + c0 + ni * 16 + lrow;
      float vj = V[j], b1j = b1[j], qv = q[(size_t)b * DECU + j];
#pragma unroll
      for (int reg = 0; reg < 4; ++reg)
        psum[mi][reg] += vj * fast_tanh(acc[mi][ni][reg] + b1j + qv);
    }
#pragma unroll
  for (int off = 1; off < 16; off <<= 1)
#pragma unroll
    for (int mi = 0; mi < 4; ++mi)
#pragma unroll
      for (int reg = 0; reg < 4; ++reg)
        psum[mi][reg] += __shfl_xor(psum[mi][reg], off);
  if (lrow == 0) {
#pragma unroll
    for (int mi = 0; mi < 4; ++mi)
#pragma unroll
      for (int reg = 0; reg < 4; ++reg)
        red[wn][r0 + mi * 16 + (lane >> 4) * 4 + reg] = psum[mi][reg];
  }
  __syncthreads();
  if (tid < 128)
    sc_part[((size_t)b * 128 + tid) * 4 + by] = red[0][tid] + red[1][tid];
}

// ---------------- ctx v4: softmax + context (bf16 enc) + xi; grid (256 b, 8 col-chunks) ----------------
__global__ __launch_bounds__(256) void k_ctx4(const float* __restrict__ sc_part,
                                              const float* __restrict__ bV,
                                              const __bf16* __restrict__ enc_bf,
                                              const int* __restrict__ x,
                                              const float* __restrict__ emb,
                                              float* __restrict__ attn_out,
                                              __bf16* __restrict__ xi_bf) {
  int b = blockIdx.x, chunk = blockIdx.y, t = threadIdx.x;
  int lane = t & 63, w = t >> 6;
  __shared__ float a_s[S_];
  __shared__ float part[4][128];
  if (t < S_) {
    float4 p = *(const float4*)&sc_part[((size_t)b * 128 + t) * 4];
    a_s[t] = bV[0] + p.x + p.y + p.z + p.w;
  }
  __syncthreads();
  float mx = -INFINITY;
  for (int s = 0; s < S_; ++s) mx = fmaxf(mx, a_s[s]);
  float sum = 0.f;
  for (int s = 0; s < S_; ++s) sum += __expf(a_s[s] - mx);
  float inv = 1.f / sum;
  __syncthreads();
  if (t < S_) {
    float av = __expf(a_s[t] - mx) * inv;
    a_s[t] = av;
    if (chunk == 0) attn_out[(size_t)b * S_ + t] = av;
  }
  __syncthreads();
  // context cols [chunk*128, chunk*128+128): wave w covers s in [w*32,+32), 2 cols/lane
  int c0 = chunk * 128;
  float a0 = 0.f, a1 = 0.f;
  const __bf16* eb = enc_bf + ((size_t)b * S_ + w * 32) * ENCD + c0 + lane * 2;
#pragma unroll 8
  for (int s = 0; s < 32; ++s) {
    bf16x2 e = *(const bf16x2*)(eb + (size_t)s * ENCD);
    float av = a_s[w * 32 + s];
    a0 = fmaf(av, (float)e[0], a0);
    a1 = fmaf(av, (float)e[1], a1);
  }
  part[w][lane * 2 + 0] = a0;
  part[w][lane * 2 + 1] = a1;
  __syncthreads();
  if (t < 128) {
    float v = part[0][t] + part[1][t] + part[2][t] + part[3][t];
    xi_bf[(size_t)b * KPADX + c0 + t] = (__bf16)v;
  }
  if (chunk == 0) {
    int xb = x[b];
    if (t < 75) {
      float4 f = *(const float4*)&emb[(size_t)xb * EMB_ + t * 4];
      bf16x4 o4 = {(__bf16)f.x, (__bf16)f.y, (__bf16)f.z, (__bf16)f.w};
      *(bf16x4*)&xi_bf[(size_t)b * KPADX + ENCD + t * 4] = o4;
    } else if (t < 80) {
      bf16x4 z = {(__bf16)0.f, (__bf16)0.f, (__bf16)0.f, (__bf16)0.f};
      *(bf16x4*)&xi_bf[(size_t)b * KPADX + INDIM + (t - 75) * 4] = z;
    }
  }
}

// ---------------- ctx v3 (fallback, f32 enc): grid (256 b, 4 col-chunks) ----------------
__global__ __launch_bounds__(256) void k_ctx3(const float* __restrict__ sc_part,
                                              const float* __restrict__ bV,
                                              const float* __restrict__ enc,
                                              const int* __restrict__ x,
                                              const float* __restrict__ emb,
                                              float* __restrict__ attn_out,
                                              __bf16* __restrict__ xi_bf) {
  int b = blockIdx.x, chunk = blockIdx.y, t = threadIdx.x;
  int lane = t & 63, w = t >> 6;
  __shared__ float a_s[S_];
  __shared__ float part[4][256];
  if (t < S_) {
    float4 p = *(const float4*)&sc_part[((size_t)b * 128 + t) * 4];
    a_s[t] = bV[0] + p.x + p.y + p.z + p.w;
  }
  __syncthreads();
  float mx = -INFINITY;
  for (int s = 0; s < S_; ++s) mx = fmaxf(mx, a_s[s]);
  float sum = 0.f;
  for (int s = 0; s < S_; ++s) sum += __expf(a_s[s] - mx);
  float inv = 1.f / sum;
  __syncthreads();
  if (t < S_) {
    float av = __expf(a_s[t] - mx) * inv;
    a_s[t] = av;
    if (chunk == 0) attn_out[(size_t)b * S_ + t] = av;
  }
  __syncthreads();
  int c0 = chunk * 256;
  float a0 = 0.f, a1 = 0.f, a2 = 0.f, a3 = 0.f;
  const float* eb = enc + ((size_t)b * S_ + w * 32) * ENCD + c0 + lane * 4;
#pragma unroll 8
  for (int s = 0; s < 32; ++s) {
    float av = a_s[w * 32 + s];
    float4 e = *(const float4*)(eb + (size_t)s * ENCD);
    a0 = fmaf(av, e.x, a0); a1 = fmaf(av, e.y, a1);
    a2 = fmaf(av, e.z, a2); a3 = fmaf(av, e.w, a3);
  }
  part[w][lane * 4 + 0] = a0; part[w][lane * 4 + 1] = a1;
  part[w][lane * 4 + 2] = a2; part[w][lane * 4 + 3] = a3;
  __syncthreads();
  float v = part[0][t] + part[1][t] + part[2][t] + part[3][t];
  xi_bf[(size_t)b * KPADX + c0 + t] = (__bf16)v;
  if (chunk == 0) {
    int xb = x[b];
    if (t < 75) {
      float4 f = *(const float4*)&emb[(size_t)xb * EMB_ + t * 4];
      bf16x4 o4 = {(__bf16)f.x, (__bf16)f.y, (__bf16)f.z, (__bf16)f.w};
      *(bf16x4*)&xi_bf[(size_t)b * KPADX + ENCD + t * 4] = o4;
    } else if (t < 80) {
      bf16x4 z = {(__bf16)0.f, (__bf16)0.f, (__bf16)0.f, (__bf16)0.f};
      *(bf16x4*)&xi_bf[(size_t)b * KPADX + INDIM + (t - 75) * 4] = z;
    }
  }
}

// ---------------- GRU gates (+ h in bf16) ----------------
__global__ __launch_bounds__(256) void k_gates(const float* __restrict__ mx,
                                               const float* __restrict__ mh,
                                               const float* __restrict__ state,
                                               float* __restrict__ h_out,
                                               __bf16* __restrict__ h_bf) {
  int idx = blockIdx.x * 256 + threadIdx.x;
  int b = idx >> 10, j = idx & 1023;
  const float* mxr = mx + (size_t)b * G3;
  const float* mhr = mh + (size_t)b * G3;
  float z = 1.f / (1.f + __expf(-(mxr[j] + mhr[j])));
  float r = 1.f / (1.f + __expf(-(mxr[UNITS + j] + mhr[UNITS + j])));
  float hh = tanhf(mxr[2 * UNITS + j] + r * mhr[2 * UNITS + j]);
  float st = state[idx];
  float h = z * st + (1.f - z) * hh;
  h_out[idx] = h;
  h_bf[idx] = (__bf16)h;
}

// ---------------- register-resident vocab softmax ----------------
__global__ __launch_bounds__(1024) void k_softmax(float* __restrict__ logits) {
  int b = blockIdx.x, t = threadIdx.x;
  int lane = t & 63, w = t >> 6;
  float4* row4 = (float4*)(logits + (size_t)b * VOCAB);  // 8000 float4
  __shared__ float redm[16];
  __shared__ float reds[16];
  float4 v[8];
  float m = -INFINITY;
#pragma unroll
  for (int i = 0; i < 8; ++i) {
    int i4 = i * 1024 + t;
    if (i4 < 8000) {
      v[i] = row4[i4];
      m = fmaxf(m, fmaxf(fmaxf(v[i].x, v[i].y), fmaxf(v[i].z, v[i].w)));
    } else {
      v[i] = make_float4(-INFINITY, -INFINITY, -INFINITY, -INFINITY);
    }
  }
#pragma unroll
  for (int o = 32; o >= 1; o >>= 1) m = fmaxf(m, __shfl_xor(m, o));
  if (lane == 0) redm[w] = m;
  __syncthreads();
  float m2 = -INFINITY;
#pragma unroll
  for (int i = 0; i < 16; ++i) m2 = fmaxf(m2, redm[i]);
  float s = 0.f;
#pragma unroll
  for (int i = 0; i < 8; ++i) {
    v[i].x = __expf(v[i].x - m2);
    v[i].y = __expf(v[i].y - m2);
    v[i].z = __expf(v[i].z - m2);
    v[i].w = __expf(v[i].w - m2);
    s += v[i].x + v[i].y + v[i].z + v[i].w;
  }
#pragma unroll
  for (int o = 32; o >= 1; o >>= 1) s += __shfl_xor(s, o);
  if (lane == 0) reds[w] = s;
  __syncthreads();
  float s2 = 0.f;
#pragma unroll
  for (int i = 0; i < 16; ++i) s2 += reds[i];
  float inv = 1.f / s2;
#pragma unroll
  for (int i = 0; i < 8; ++i) {
    int i4 = i * 1024 + t;
    if (i4 < 8000)
      row4[i4] = make_float4(v[i].x * inv, v[i].y * inv, v[i].z * inv, v[i].w * inv);
  }
}

extern "C" void kernel_launch(void* const* d_in, const int* in_sizes, int n_in,
                              void* d_out, int out_size, void* d_ws, size_t ws_size,
                              hipStream_t stream) {
  const int*   x     = (const int*)d_in[0];
  const float* state = (const float*)d_in[1];
  const float* enc   = (const float*)d_in[2];
  const float* emb   = (const float*)d_in[3];
  const float* W1    = (const float*)d_in[4];
  const float* b1    = (const float*)d_in[5];
  const float* W2    = (const float*)d_in[6];
  const float* b2    = (const float*)d_in[7];
  const float* V     = (const float*)d_in[8];
  const float* bV    = (const float*)d_in[9];
  const float* gru_k = (const float*)d_in[10];
  const float* gru_rk= (const float*)d_in[11];
  const float* gru_b = (const float*)d_in[12];
  const float* fc_W  = (const float*)d_in[13];
  const float* fc_b  = (const float*)d_in[14];

  float* out   = (float*)d_out;
  float* probs = out;                               // 256*32000
  float* h_out = out + (size_t)B_ * VOCAB;          // 256*1024
  float* attn  = h_out + (size_t)B_ * UNITS;        // 256*128

  // ws layout (bytes), all offsets 16B-aligned:
  char* wsb = (char*)d_ws;
  const size_t ENC_BF_BYTES = (size_t)B_ * S_ * ENCD * 2;        // 67,108,864
  __bf16* enc_bf  = (__bf16*)wsb;                                 // [0, 64MB)
  __bf16* W1t     = (__bf16*)(wsb + ENC_BF_BYTES);                // 1MB
  __bf16* state_bf= (__bf16*)(wsb + ENC_BF_BYTES + 1048576);      // 0.5MB
  __bf16* xi_bf   = (__bf16*)(wsb + ENC_BF_BYTES + 1572864);      // 688128
  __bf16* h_bf    = (__bf16*)(wsb + ENC_BF_BYTES + 2260992);      // 0.5MB
  float*  q       = (float*)(wsb + ENC_BF_BYTES + 2785280);       // 0.5MB
  float*  sc_part = (float*)(wsb + ENC_BF_BYTES + 3309568);       // 0.5MB
  float*  mx      = (float*)(wsb + ENC_BF_BYTES + 3833856);       // 3MB
  float*  mh      = (float*)(wsb + ENC_BF_BYTES + 6979584);       // 3MB
  const size_t NEED = ENC_BF_BYTES + 6979584 + 3145728;           // ~77.2MB
  bool big = ws_size >= NEED;
  if (!big) {
    // fallback layout without enc_bf
    W1t      = (__bf16*)wsb;
    state_bf = (__bf16*)(wsb + 1048576);
    xi_bf    = (__bf16*)(wsb + 1572864);
    h_bf     = (__bf16*)(wsb + 2260992);
    q        = (float*)(wsb + 2785280);
    sc_part  = (float*)(wsb + 3309568);
    mx       = (float*)(wsb + 3833856);
    mh       = (float*)(wsb + 6979584);
  }

  if (big) k_cvt_enc<<<4096, 256, 0, stream>>>(enc, enc_bf);
  k_cvt_state<<<256, 256, 0, stream>>>(state, state_bf);
  k_w1t<<<512, 1024, 0, stream>>>(W1, W1t);
  // q = state @ W2 + b2
  k_gemm<64><<<dim3(4, 8), 512, 0, stream>>>(state_bf, UNITS, W2, b2, q, UNITS, DECU);
  // score partials
  if (big) k_score6<<<dim3(B_, 4), 256, 0, stream>>>(enc_bf, W1t, b1, q, V, sc_part);
  else     k_score2<<<dim3(B_, 4), 256, 0, stream>>>(enc, W1t, b1, q, V, sc_part);
  // softmax + context + xi
  if (big) k_ctx4<<<dim3(B_, 8), 256, 0, stream>>>(sc_part, bV, enc_bf, x, emb, attn, xi_bf);
  else     k_ctx3<<<dim3(B_, 4), 256, 0, stream>>>(sc_part, bV, enc, x, emb, attn, xi_bf);
  // GRU GEMMs
  k_gemm<64><<<dim3(4, 48), 512, 0, stream>>>(xi_bf, KPADX, gru_k, gru_b, mx, INDIM, G3);
  k_gemm<64><<<dim3(4, 48), 512, 0, stream>>>(state_bf, UNITS, gru_rk, gru_b + G3, mh, UNITS, G3);
  // gates -> h
  k_gates<<<(B_ * UNITS) / 256, 256, 0, stream>>>(mx, mh, state, h_out, h_bf);
  // FC logits
  k_gemm<256><<<dim3(1, VOCAB / 64), 512, 0, stream>>>(h_bf, UNITS, fc_W, fc_b, probs, UNITS, VOCAB);
  // vocab softmax
  k_softmax<<<B_, 1024, 0, stream>>>(probs);
}